// Round 1
// baseline (3436.801 us; speedup 1.0000x reference)
//
#include <hip/hip_runtime.h>
#include <hip/hip_bf16.h>
#include <cstddef>
#include <cstdint>

// Problem constants (from reference)
#define N0 100000
#define N1 25000
#define N2 6250
#define N3 1600
#define DEG 16
#define D_IN 512
#define D_H 256

// ---------------------------------------------------------------------------
// Scatter-add: for each edge e, agg[dst[e]][:] += h[src[e]][:], deg[dst[e]] += 1
// block = 256 threads; each block handles EPB = 256/(K/4) edges.
// ---------------------------------------------------------------------------
__global__ void scatter_add_kernel(const float* __restrict__ h,
                                   const int* __restrict__ src,
                                   const int* __restrict__ dst,
                                   float* __restrict__ agg,
                                   float* __restrict__ deg,
                                   int E, int K)
{
    const int kq   = K >> 2;               // float4s per row
    const int epb  = 256 / kq;             // edges per block
    const int eloc = threadIdx.x / kq;     // which edge within block
    const int koff = threadIdx.x % kq;     // which float4 within row
    const int e    = blockIdx.x * epb + eloc;
    if (e >= E) return;

    const int s = src[e];
    const int d = dst[e];

    const float4 v = *reinterpret_cast<const float4*>(h + (size_t)s * K + (size_t)koff * 4);
    float* ad = agg + (size_t)d * K + (size_t)koff * 4;
    atomicAdd(ad + 0, v.x);
    atomicAdd(ad + 1, v.y);
    atomicAdd(ad + 2, v.z);
    atomicAdd(ad + 3, v.w);
    if (koff == 0) atomicAdd(deg + d, 1.0f);
}

// ---------------------------------------------------------------------------
// mean = agg / max(deg,1), in place. One float4 per thread (grid-stride-free,
// grid sized exactly).
// ---------------------------------------------------------------------------
__global__ void mean_div_kernel(float* __restrict__ agg,
                                const float* __restrict__ deg,
                                int n, int K)
{
    const size_t total = (size_t)n * (K >> 2);
    const size_t i = (size_t)blockIdx.x * blockDim.x + threadIdx.x;
    if (i >= total) return;
    const int row = (int)(i / (K >> 2));
    const float r = 1.0f / fmaxf(deg[row], 1.0f);
    float4* p = reinterpret_cast<float4*>(agg) + i;
    float4 v = *p;
    v.x *= r; v.y *= r; v.z *= r; v.w *= r;
    *p = v;
}

// ---------------------------------------------------------------------------
// Fused GEMM:  C[MxN] = A[MxK] @ Ws[KxN]  (+ Mean[MxK] @ Wn[KxN])  + bias[N]
// optional ReLU.  64x64 block tile, BK=16, 256 threads, 4x4 micro-tile.
// A/Mean row stride == K. All row-major fp32.
// ---------------------------------------------------------------------------
#define BM 64
#define BN 64
#define BK 16

template<bool HAS_MEAN, bool RELU>
__global__ __launch_bounds__(256)
void sage_gemm_kernel(const float* __restrict__ A,
                      const float* __restrict__ Mn,
                      const float* __restrict__ Ws,
                      const float* __restrict__ Wn,
                      const float* __restrict__ bias,
                      float* __restrict__ C,
                      int M, int N, int K)
{
    __shared__ float sA[BK][BM + 1];
    __shared__ float sB[BK][BN];

    const int bm  = blockIdx.y * BM;
    const int bn  = blockIdx.x * BN;
    const int tid = threadIdx.x;
    const int tx  = tid & 15;   // 16 cols of threads -> 4 outputs each
    const int ty  = tid >> 4;   // 16 rows of threads -> 4 outputs each

    float acc[4][4] = {};

    const int npass = HAS_MEAN ? 2 : 1;
    for (int pass = 0; pass < npass; ++pass) {
        const float* __restrict__ Ap = (pass == 0) ? A  : Mn;
        const float* __restrict__ Wp = (pass == 0) ? Ws : Wn;

        for (int k0 = 0; k0 < K; k0 += BK) {
            // --- load A tile: rows bm..bm+63, k0..k0+15 ---
            {
                const int m  = tid & 63;    // row in tile
                const int kg = tid >> 6;    // 0..3, group of 4 k
                const int row = bm + m;
                float4 v = make_float4(0.f, 0.f, 0.f, 0.f);
                if (row < M)
                    v = *reinterpret_cast<const float4*>(Ap + (size_t)row * K + k0 + kg * 4);
                sA[kg * 4 + 0][m] = v.x;
                sA[kg * 4 + 1][m] = v.y;
                sA[kg * 4 + 2][m] = v.z;
                sA[kg * 4 + 3][m] = v.w;
            }
            // --- load W tile: k0..k0+15, cols bn..bn+63 ---
            {
                const int k  = tid >> 4;    // 0..15
                const int n4 = tid & 15;    // 0..15 -> 4 cols
                const float4 v = *reinterpret_cast<const float4*>(
                    Wp + (size_t)(k0 + k) * N + bn + n4 * 4);
                *reinterpret_cast<float4*>(&sB[k][n4 * 4]) = v;
            }
            __syncthreads();

            #pragma unroll
            for (int k = 0; k < BK; ++k) {
                float a0 = sA[k][ty * 4 + 0];
                float a1 = sA[k][ty * 4 + 1];
                float a2 = sA[k][ty * 4 + 2];
                float a3 = sA[k][ty * 4 + 3];
                float b0 = sB[k][tx * 4 + 0];
                float b1 = sB[k][tx * 4 + 1];
                float b2 = sB[k][tx * 4 + 2];
                float b3 = sB[k][tx * 4 + 3];
                acc[0][0] += a0 * b0; acc[0][1] += a0 * b1; acc[0][2] += a0 * b2; acc[0][3] += a0 * b3;
                acc[1][0] += a1 * b0; acc[1][1] += a1 * b1; acc[1][2] += a1 * b2; acc[1][3] += a1 * b3;
                acc[2][0] += a2 * b0; acc[2][1] += a2 * b1; acc[2][2] += a2 * b2; acc[2][3] += a2 * b3;
                acc[3][0] += a3 * b0; acc[3][1] += a3 * b1; acc[3][2] += a3 * b2; acc[3][3] += a3 * b3;
            }
            __syncthreads();
        }
    }

    // --- epilogue ---
    #pragma unroll
    for (int i = 0; i < 4; ++i) {
        const int row = bm + ty * 4 + i;
        if (row >= M) continue;
        #pragma unroll
        for (int j = 0; j < 4; ++j) {
            const int col = bn + tx * 4 + j;
            float v = acc[i][j] + bias[col];
            if (RELU) v = fmaxf(v, 0.0f);
            C[(size_t)row * N + col] = v;
        }
    }
}

// ---------------------------------------------------------------------------
// Workspace layout helpers (bytes, 256-aligned)
// ---------------------------------------------------------------------------
static constexpr size_t align256(size_t x) { return (x + 255) & ~(size_t)255; }

extern "C" void kernel_launch(void* const* d_in, const int* in_sizes, int n_in,
                              void* d_out, int out_size, void* d_ws, size_t ws_size,
                              hipStream_t stream)
{
    // inputs per setup_inputs() order
    const float* x    = (const float*)d_in[0];
    const int*  src0  = (const int*)d_in[1];
    const int*  dst0  = (const int*)d_in[2];
    const int*  src1  = (const int*)d_in[3];
    const int*  dst1  = (const int*)d_in[4];
    const int*  src2  = (const int*)d_in[5];
    const int*  dst2  = (const int*)d_in[6];
    const float* Ws0  = (const float*)d_in[7];
    const float* Wn0  = (const float*)d_in[8];
    const float* b0   = (const float*)d_in[9];
    const float* Ws1  = (const float*)d_in[10];
    const float* Wn1  = (const float*)d_in[11];
    const float* b1   = (const float*)d_in[12];
    const float* Ws2  = (const float*)d_in[13];
    const float* Wn2  = (const float*)d_in[14];
    const float* b2   = (const float*)d_in[15];
    const float* W_fc = (const float*)d_in[16];
    const float* b_fc = (const float*)d_in[17];
    float* out = (float*)d_out;

    // workspace layout: [agg0 deg0 agg1 deg1 agg2 deg2 | h0 h1 h2]
    char* ws = (char*)d_ws;
    size_t off = 0;
    const size_t agg0_off = off; off = align256(off + (size_t)N1 * D_IN * 4);
    const size_t deg0_off = off; off = align256(off + (size_t)N1 * 4);
    const size_t agg1_off = off; off = align256(off + (size_t)N2 * D_H * 4);
    const size_t deg1_off = off; off = align256(off + (size_t)N2 * 4);
    const size_t agg2_off = off; off = align256(off + (size_t)N3 * D_H * 4);
    const size_t deg2_off = off; off = align256(off + (size_t)N3 * 4);
    const size_t zero_bytes = off;               // everything above must be zeroed
    const size_t h0_off   = off; off = align256(off + (size_t)N1 * D_H * 4);
    const size_t h1_off   = off; off = align256(off + (size_t)N2 * D_H * 4);
    const size_t h2_off   = off; off = align256(off + (size_t)N3 * D_H * 4);

    float* agg0 = (float*)(ws + agg0_off);
    float* deg0 = (float*)(ws + deg0_off);
    float* agg1 = (float*)(ws + agg1_off);
    float* deg1 = (float*)(ws + deg1_off);
    float* agg2 = (float*)(ws + agg2_off);
    float* deg2 = (float*)(ws + deg2_off);
    float* h0   = (float*)(ws + h0_off);
    float* h1   = (float*)(ws + h1_off);
    float* h2   = (float*)(ws + h2_off);

    // zero accumulators (one contiguous region)
    hipMemsetAsync(d_ws, 0, zero_bytes, stream);

    // ---------------- layer 0 ----------------
    {
        const int E = N1 * DEG;                        // 400000
        const int epb = 256 / (D_IN / 4);              // 2 edges / block
        scatter_add_kernel<<<(E + epb - 1) / epb, 256, 0, stream>>>(
            x, src0, dst0, agg0, deg0, E, D_IN);
        const size_t tot4 = (size_t)N1 * (D_IN / 4);
        mean_div_kernel<<<(tot4 + 255) / 256, 256, 0, stream>>>(agg0, deg0, N1, D_IN);
        dim3 grid(D_H / BN, (N1 + BM - 1) / BM);
        sage_gemm_kernel<true, true><<<grid, 256, 0, stream>>>(
            x, agg0, Ws0, Wn0, b0, h0, N1, D_H, D_IN);
    }
    // ---------------- layer 1 ----------------
    {
        const int E = N2 * DEG;                        // 100000
        const int epb = 256 / (D_H / 4);               // 4 edges / block
        scatter_add_kernel<<<(E + epb - 1) / epb, 256, 0, stream>>>(
            h0, src1, dst1, agg1, deg1, E, D_H);
        const size_t tot4 = (size_t)N2 * (D_H / 4);
        mean_div_kernel<<<(tot4 + 255) / 256, 256, 0, stream>>>(agg1, deg1, N2, D_H);
        dim3 grid(D_H / BN, (N2 + BM - 1) / BM);
        sage_gemm_kernel<true, true><<<grid, 256, 0, stream>>>(
            h0, agg1, Ws1, Wn1, b1, h1, N2, D_H, D_H);
    }
    // ---------------- layer 2 (no relu) ----------------
    {
        const int E = N3 * DEG;                        // 25600
        const int epb = 256 / (D_H / 4);
        scatter_add_kernel<<<(E + epb - 1) / epb, 256, 0, stream>>>(
            h1, src2, dst2, agg2, deg2, E, D_H);
        const size_t tot4 = (size_t)N3 * (D_H / 4);
        mean_div_kernel<<<(tot4 + 255) / 256, 256, 0, stream>>>(agg2, deg2, N3, D_H);
        dim3 grid(D_H / BN, (N3 + BM - 1) / BM);
        sage_gemm_kernel<true, false><<<grid, 256, 0, stream>>>(
            h1, agg2, Ws2, Wn2, b2, h2, N3, D_H, D_H);
    }
    // ---------------- final FC ----------------
    {
        dim3 grid(D_H / BN, (N3 + BM - 1) / BM);
        sage_gemm_kernel<false, false><<<grid, 256, 0, stream>>>(
            h2, nullptr, W_fc, nullptr, b_fc, out, N3, D_H, D_H);
    }
}

// Round 2
// 614.903 us; speedup vs baseline: 5.5892x; 5.5892x over previous
//
#include <hip/hip_runtime.h>
#include <hip/hip_bf16.h>
#include <cstddef>
#include <cstdint>

// Problem constants (from reference)
#define N0 100000
#define N1 25000
#define N2 6250
#define N3 1600
#define DEG 16
#define D_IN 512
#define D_H 256

// ---------------------------------------------------------------------------
// CSR build step 1: histogram of dst
// ---------------------------------------------------------------------------
__global__ void hist_kernel(const int* __restrict__ dst, int* __restrict__ cnt, int E)
{
    const int i = blockIdx.x * blockDim.x + threadIdx.x;
    if (i < E) atomicAdd(&cnt[dst[i]], 1);
}

// ---------------------------------------------------------------------------
// CSR build step 2: exclusive scan of cnt -> ptr (n+1 entries). Single block.
// ---------------------------------------------------------------------------
__global__ __launch_bounds__(1024)
void exclusive_scan_kernel(const int* __restrict__ cnt, int* __restrict__ ptr, int n)
{
    __shared__ int buf[1024];
    __shared__ int s_carry;
    if (threadIdx.x == 0) s_carry = 0;
    __syncthreads();
    for (int base = 0; base < n; base += 1024) {
        const int i = base + threadIdx.x;
        const int v = (i < n) ? cnt[i] : 0;
        buf[threadIdx.x] = v;
        __syncthreads();
        // inclusive Hillis-Steele scan
        for (int off = 1; off < 1024; off <<= 1) {
            const int t = (threadIdx.x >= (unsigned)off) ? buf[threadIdx.x - off] : 0;
            __syncthreads();
            buf[threadIdx.x] += t;
            __syncthreads();
        }
        const int carry = s_carry;
        if (i < n) ptr[i] = carry + buf[threadIdx.x] - v;   // exclusive
        __syncthreads();
        if (threadIdx.x == 0) s_carry = carry + buf[1023];
        __syncthreads();
    }
    if (threadIdx.x == 0) ptr[n] = s_carry;
}

// ---------------------------------------------------------------------------
// CSR build step 3a: cursor = ptr (first n entries)
// ---------------------------------------------------------------------------
__global__ void copy_int_kernel(const int* __restrict__ a, int* __restrict__ b, int n)
{
    const int i = blockIdx.x * blockDim.x + threadIdx.x;
    if (i < n) b[i] = a[i];
}

// ---------------------------------------------------------------------------
// CSR build step 3b: scatter src values into dst-ordered buckets
// ---------------------------------------------------------------------------
__global__ void fill_kernel(const int* __restrict__ src, const int* __restrict__ dst,
                            int* __restrict__ cursor, int* __restrict__ esrc, int E)
{
    const int i = blockIdx.x * blockDim.x + threadIdx.x;
    if (i < E) {
        const int p = atomicAdd(&cursor[dst[i]], 1);
        esrc[p] = src[i];
    }
}

// ---------------------------------------------------------------------------
// Gather-based mean aggregation: one TPN-lane group per dst node.
//   mean[node][:] = sum_{e in CSR bucket} h[esrc[e]][:] / max(deg,1)
// No float atomics, exactly one write per output element.
// ---------------------------------------------------------------------------
template<int K>
__global__ __launch_bounds__(256)
void csr_mean_kernel(const float* __restrict__ h,
                     const int* __restrict__ esrc,
                     const int* __restrict__ ptr,
                     float* __restrict__ mean,
                     int n)
{
    constexpr int TPN = K / 4;          // lanes per node (float4 each)
    constexpr int NPB = 256 / TPN;      // nodes per block
    const int node = blockIdx.x * NPB + threadIdx.x / TPN;
    const int lane = threadIdx.x % TPN;
    if (node >= n) return;

    const int beg = ptr[node];
    const int end = ptr[node + 1];

    float4 acc = make_float4(0.f, 0.f, 0.f, 0.f);
    for (int p = beg; p < end; ++p) {
        const int s = esrc[p];
        const float4 v = *reinterpret_cast<const float4*>(h + (size_t)s * K + (size_t)lane * 4);
        acc.x += v.x; acc.y += v.y; acc.z += v.z; acc.w += v.w;
    }
    const float r = 1.0f / fmaxf((float)(end - beg), 1.0f);
    acc.x *= r; acc.y *= r; acc.z *= r; acc.w *= r;
    *reinterpret_cast<float4*>(mean + (size_t)node * K + (size_t)lane * 4) = acc;
}

// ---------------------------------------------------------------------------
// Fused GEMM:  C[MxN] = A[MxK] @ Ws[KxN]  (+ Mean[MxK] @ Wn[KxN])  + bias[N]
// optional ReLU.  64x64 block tile, BK=16, 256 threads, 4x4 micro-tile.
// ---------------------------------------------------------------------------
#define BM 64
#define BN 64
#define BK 16

template<bool HAS_MEAN, bool RELU>
__global__ __launch_bounds__(256)
void sage_gemm_kernel(const float* __restrict__ A,
                      const float* __restrict__ Mn,
                      const float* __restrict__ Ws,
                      const float* __restrict__ Wn,
                      const float* __restrict__ bias,
                      float* __restrict__ C,
                      int M, int N, int K)
{
    __shared__ float sA[BK][BM + 1];
    __shared__ float sB[BK][BN];

    const int bm  = blockIdx.y * BM;
    const int bn  = blockIdx.x * BN;
    const int tid = threadIdx.x;
    const int tx  = tid & 15;
    const int ty  = tid >> 4;

    float acc[4][4] = {};

    const int npass = HAS_MEAN ? 2 : 1;
    for (int pass = 0; pass < npass; ++pass) {
        const float* __restrict__ Ap = (pass == 0) ? A  : Mn;
        const float* __restrict__ Wp = (pass == 0) ? Ws : Wn;

        for (int k0 = 0; k0 < K; k0 += BK) {
            {
                const int m  = tid & 63;
                const int kg = tid >> 6;
                const int row = bm + m;
                float4 v = make_float4(0.f, 0.f, 0.f, 0.f);
                if (row < M)
                    v = *reinterpret_cast<const float4*>(Ap + (size_t)row * K + k0 + kg * 4);
                sA[kg * 4 + 0][m] = v.x;
                sA[kg * 4 + 1][m] = v.y;
                sA[kg * 4 + 2][m] = v.z;
                sA[kg * 4 + 3][m] = v.w;
            }
            {
                const int k  = tid >> 4;
                const int n4 = tid & 15;
                const float4 v = *reinterpret_cast<const float4*>(
                    Wp + (size_t)(k0 + k) * N + bn + n4 * 4);
                *reinterpret_cast<float4*>(&sB[k][n4 * 4]) = v;
            }
            __syncthreads();

            #pragma unroll
            for (int k = 0; k < BK; ++k) {
                float a0 = sA[k][ty * 4 + 0];
                float a1 = sA[k][ty * 4 + 1];
                float a2 = sA[k][ty * 4 + 2];
                float a3 = sA[k][ty * 4 + 3];
                float b0 = sB[k][tx * 4 + 0];
                float b1 = sB[k][tx * 4 + 1];
                float b2 = sB[k][tx * 4 + 2];
                float b3 = sB[k][tx * 4 + 3];
                acc[0][0] += a0 * b0; acc[0][1] += a0 * b1; acc[0][2] += a0 * b2; acc[0][3] += a0 * b3;
                acc[1][0] += a1 * b0; acc[1][1] += a1 * b1; acc[1][2] += a1 * b2; acc[1][3] += a1 * b3;
                acc[2][0] += a2 * b0; acc[2][1] += a2 * b1; acc[2][2] += a2 * b2; acc[2][3] += a2 * b3;
                acc[3][0] += a3 * b0; acc[3][1] += a3 * b1; acc[3][2] += a3 * b2; acc[3][3] += a3 * b3;
            }
            __syncthreads();
        }
    }

    #pragma unroll
    for (int i = 0; i < 4; ++i) {
        const int row = bm + ty * 4 + i;
        if (row >= M) continue;
        #pragma unroll
        for (int j = 0; j < 4; ++j) {
            const int col = bn + tx * 4 + j;
            float v = acc[i][j] + bias[col];
            if (RELU) v = fmaxf(v, 0.0f);
            C[(size_t)row * N + col] = v;
        }
    }
}

static constexpr size_t align256(size_t x) { return (x + 255) & ~(size_t)255; }

extern "C" void kernel_launch(void* const* d_in, const int* in_sizes, int n_in,
                              void* d_out, int out_size, void* d_ws, size_t ws_size,
                              hipStream_t stream)
{
    const float* x    = (const float*)d_in[0];
    const int*  src0  = (const int*)d_in[1];
    const int*  dst0  = (const int*)d_in[2];
    const int*  src1  = (const int*)d_in[3];
    const int*  dst1  = (const int*)d_in[4];
    const int*  src2  = (const int*)d_in[5];
    const int*  dst2  = (const int*)d_in[6];
    const float* Ws0  = (const float*)d_in[7];
    const float* Wn0  = (const float*)d_in[8];
    const float* b0   = (const float*)d_in[9];
    const float* Ws1  = (const float*)d_in[10];
    const float* Wn1  = (const float*)d_in[11];
    const float* b1   = (const float*)d_in[12];
    const float* Ws2  = (const float*)d_in[13];
    const float* Wn2  = (const float*)d_in[14];
    const float* b2   = (const float*)d_in[15];
    const float* W_fc = (const float*)d_in[16];
    const float* b_fc = (const float*)d_in[17];
    float* out = (float*)d_out;

    // --- workspace layout (buffers reused across layers) ---
    // cnt[N1] | ptr[N1+1] | cursor[N1] | esrc[E0max] | mean[N1*512] | h0 | h1 | h2
    char* ws = (char*)d_ws;
    size_t off = 0;
    const size_t cnt_off  = off; off = align256(off + (size_t)N1 * 4);
    const size_t ptr_off  = off; off = align256(off + (size_t)(N1 + 1) * 4);
    const size_t cur_off  = off; off = align256(off + (size_t)N1 * 4);
    const size_t esrc_off = off; off = align256(off + (size_t)(N1 * DEG) * 4);
    const size_t mean_off = off; off = align256(off + (size_t)N1 * D_IN * 4);
    const size_t h0_off   = off; off = align256(off + (size_t)N1 * D_H * 4);
    const size_t h1_off   = off; off = align256(off + (size_t)N2 * D_H * 4);
    const size_t h2_off   = off; off = align256(off + (size_t)N3 * D_H * 4);

    int*   cnt    = (int*)(ws + cnt_off);
    int*   ptr    = (int*)(ws + ptr_off);
    int*   cursor = (int*)(ws + cur_off);
    int*   esrc   = (int*)(ws + esrc_off);
    float* mean   = (float*)(ws + mean_off);
    float* h0     = (float*)(ws + h0_off);
    float* h1     = (float*)(ws + h1_off);
    float* h2     = (float*)(ws + h2_off);

    // ================= layer 0 =================
    {
        const int E = N1 * DEG, n = N1, K = D_IN;
        hipMemsetAsync(cnt, 0, (size_t)n * 4, stream);
        hist_kernel<<<(E + 255) / 256, 256, 0, stream>>>(dst0, cnt, E);
        exclusive_scan_kernel<<<1, 1024, 0, stream>>>(cnt, ptr, n);
        copy_int_kernel<<<(n + 255) / 256, 256, 0, stream>>>(ptr, cursor, n);
        fill_kernel<<<(E + 255) / 256, 256, 0, stream>>>(src0, dst0, cursor, esrc, E);
        constexpr int NPB = 256 / (D_IN / 4);   // 2 nodes / block
        csr_mean_kernel<D_IN><<<(n + NPB - 1) / NPB, 256, 0, stream>>>(x, esrc, ptr, mean, n);
        dim3 grid(D_H / BN, (n + BM - 1) / BM);
        sage_gemm_kernel<true, true><<<grid, 256, 0, stream>>>(
            x, mean, Ws0, Wn0, b0, h0, n, D_H, K);
    }
    // ================= layer 1 =================
    {
        const int E = N2 * DEG, n = N2, K = D_H;
        hipMemsetAsync(cnt, 0, (size_t)n * 4, stream);
        hist_kernel<<<(E + 255) / 256, 256, 0, stream>>>(dst1, cnt, E);
        exclusive_scan_kernel<<<1, 1024, 0, stream>>>(cnt, ptr, n);
        copy_int_kernel<<<(n + 255) / 256, 256, 0, stream>>>(ptr, cursor, n);
        fill_kernel<<<(E + 255) / 256, 256, 0, stream>>>(src1, dst1, cursor, esrc, E);
        constexpr int NPB = 256 / (D_H / 4);    // 4 nodes / block
        csr_mean_kernel<D_H><<<(n + NPB - 1) / NPB, 256, 0, stream>>>(h0, esrc, ptr, mean, n);
        dim3 grid(D_H / BN, (n + BM - 1) / BM);
        sage_gemm_kernel<true, true><<<grid, 256, 0, stream>>>(
            h0, mean, Ws1, Wn1, b1, h1, n, D_H, K);
    }
    // ================= layer 2 (no relu) =================
    {
        const int E = N3 * DEG, n = N3, K = D_H;
        hipMemsetAsync(cnt, 0, (size_t)n * 4, stream);
        hist_kernel<<<(E + 255) / 256, 256, 0, stream>>>(dst2, cnt, E);
        exclusive_scan_kernel<<<1, 1024, 0, stream>>>(cnt, ptr, n);
        copy_int_kernel<<<(n + 255) / 256, 256, 0, stream>>>(ptr, cursor, n);
        fill_kernel<<<(E + 255) / 256, 256, 0, stream>>>(src2, dst2, cursor, esrc, E);
        constexpr int NPB = 256 / (D_H / 4);
        csr_mean_kernel<D_H><<<(n + NPB - 1) / NPB, 256, 0, stream>>>(h1, esrc, ptr, mean, n);
        dim3 grid(D_H / BN, (n + BM - 1) / BM);
        sage_gemm_kernel<true, false><<<grid, 256, 0, stream>>>(
            h1, mean, Ws2, Wn2, b2, h2, n, D_H, K);
    }
    // ================= final FC =================
    {
        dim3 grid(D_H / BN, (N3 + BM - 1) / BM);
        sage_gemm_kernel<false, false><<<grid, 256, 0, stream>>>(
            h2, nullptr, W_fc, nullptr, b_fc, out, N3, D_H, D_H);
    }
}

// Round 3
// 365.796 us; speedup vs baseline: 9.3954x; 1.6810x over previous
//
#include <hip/hip_runtime.h>
#include <hip/hip_bf16.h>
#include <cstddef>
#include <cstdint>

// Problem constants
#define N0 100000
#define N1 25000
#define N2 6250
#define N3 1600
#define DEG 16
#define D_IN 512
#define D_H 256

#define E0 (N1*DEG)   // 400000
#define E1 (N2*DEG)   // 100000
#define E2 (N3*DEG)   // 25600

typedef _Float16 half_t;
typedef __attribute__((ext_vector_type(8))) _Float16 f16x8;
typedef __attribute__((ext_vector_type(4))) _Float16 f16x4;
typedef __attribute__((ext_vector_type(4))) float f32x4;

// ---------------------------------------------------------------------------
// Fused CSR build (all 3 layers): hist -> scan -> fill
// ---------------------------------------------------------------------------
__global__ void hist3_kernel(const int* __restrict__ d0, const int* __restrict__ d1,
                             const int* __restrict__ d2,
                             int* __restrict__ c0, int* __restrict__ c1, int* __restrict__ c2)
{
    const int i = blockIdx.x * 256 + threadIdx.x;
    if (i < E0)            atomicAdd(&c0[d0[i]], 1);
    else if (i < E0 + E1)  atomicAdd(&c1[d1[i - E0]], 1);
    else if (i < E0 + E1 + E2) atomicAdd(&c2[d2[i - E0 - E1]], 1);
}

__global__ void fill3_kernel(const int* __restrict__ s0, const int* __restrict__ d0,
                             const int* __restrict__ s1, const int* __restrict__ d1,
                             const int* __restrict__ s2, const int* __restrict__ d2,
                             int* __restrict__ u0, int* __restrict__ u1, int* __restrict__ u2,
                             int* __restrict__ e0, int* __restrict__ e1, int* __restrict__ e2)
{
    const int i = blockIdx.x * 256 + threadIdx.x;
    if (i < E0) {
        const int p = atomicAdd(&u0[d0[i]], 1); e0[p] = s0[i];
    } else if (i < E0 + E1) {
        const int j = i - E0;
        const int p = atomicAdd(&u1[d1[j]], 1); e1[p] = s1[j];
    } else if (i < E0 + E1 + E2) {
        const int j = i - E0 - E1;
        const int p = atomicAdd(&u2[d2[j]], 1); e2[p] = s2[j];
    }
}

// 3-phase block scan; block b handles layer b. Writes ptr[0..n] and cursor[0..n).
__global__ __launch_bounds__(1024)
void scan3_kernel(const int* __restrict__ c0, int* __restrict__ p0, int* __restrict__ u0,
                  const int* __restrict__ c1, int* __restrict__ p1, int* __restrict__ u1,
                  const int* __restrict__ c2, int* __restrict__ p2, int* __restrict__ u2)
{
    const int b = blockIdx.x;
    const int* cnt = (b == 0) ? c0 : (b == 1) ? c1 : c2;
    int* ptr = (b == 0) ? p0 : (b == 1) ? p1 : p2;
    int* cur = (b == 0) ? u0 : (b == 1) ? u1 : u2;
    const int n = (b == 0) ? N1 : (b == 1) ? N2 : N3;

    const int t = threadIdx.x;
    const int chunk = (n + 1023) >> 10;
    const int beg = t * chunk;
    const int end = min(n, beg + chunk);

    int sum = 0;
    for (int i = beg; i < end; ++i) sum += cnt[i];

    const int lane = t & 63, wid = t >> 6;
    int inc = sum;
    #pragma unroll
    for (int d = 1; d < 64; d <<= 1) {
        int u = __shfl_up(inc, d, 64);
        if (lane >= d) inc += u;
    }
    __shared__ int wtot[16];
    __shared__ int total_s;
    if (lane == 63) wtot[wid] = inc;
    __syncthreads();
    if (wid == 0) {
        int w = (lane < 16) ? wtot[lane] : 0;
        int ws = w;
        #pragma unroll
        for (int d = 1; d < 16; d <<= 1) {
            int u = __shfl_up(ws, d, 64);
            if (lane >= d) ws += u;
        }
        if (lane < 16) wtot[lane] = ws - w;   // exclusive wave offset
        if (lane == 15) total_s = ws;         // block total
    }
    __syncthreads();
    int run = (inc - sum) + wtot[wid];
    for (int i = beg; i < end; ++i) {
        ptr[i] = run; cur[i] = run;
        run += cnt[i];
    }
    if (t == 0) ptr[n] = total_s;
}

// ---------------------------------------------------------------------------
// Conversions: fp32 -> fp16
// ---------------------------------------------------------------------------
__global__ __launch_bounds__(256)
void xconv_kernel(const float* __restrict__ x, half_t* __restrict__ xh, int n8)
{
    const int id = blockIdx.x * 256 + threadIdx.x;
    if (id >= n8) return;
    const float4* p = reinterpret_cast<const float4*>(x) + (size_t)id * 2;
    const float4 a = p[0], b = p[1];
    f16x8 o;
    o[0] = (half_t)a.x; o[1] = (half_t)a.y; o[2] = (half_t)a.z; o[3] = (half_t)a.w;
    o[4] = (half_t)b.x; o[5] = (half_t)b.y; o[6] = (half_t)b.z; o[7] = (half_t)b.w;
    *(reinterpret_cast<f16x8*>(xh) + id) = o;
}

// transpose+convert 7 weight matrices [K][256] fp32 -> [256][K] fp16
__global__ __launch_bounds__(256)
void wconv_kernel(const float* s0, const float* s1, const float* s2, const float* s3,
                  const float* s4, const float* s5, const float* s6,
                  half_t* t0, half_t* t1, half_t* t2, half_t* t3,
                  half_t* t4, half_t* t5, half_t* t6)
{
    const int id = blockIdx.x * 256 + threadIdx.x;
    const float* src; half_t* dst; int kb; int e;
    if (id < 131072)      { src = s0; dst = t0; kb = 9; e = id; }
    else if (id < 262144) { src = s1; dst = t1; kb = 9; e = id - 131072; }
    else if (id < 327680) { src = s2; dst = t2; kb = 8; e = id - 262144; }
    else if (id < 393216) { src = s3; dst = t3; kb = 8; e = id - 327680; }
    else if (id < 458752) { src = s4; dst = t4; kb = 8; e = id - 393216; }
    else if (id < 524288) { src = s5; dst = t5; kb = 8; e = id - 458752; }
    else if (id < 589824) { src = s6; dst = t6; kb = 8; e = id - 524288; }
    else return;
    const int K = 1 << kb;
    const int nn = e >> kb, k = e & (K - 1);
    dst[((size_t)nn << kb) + k] = (half_t)src[(size_t)k * 256 + nn];
}

// ---------------------------------------------------------------------------
// CSR gather-mean. f32-input variant (layer 0) and f16-input variant (1,2).
// Output fp16.
// ---------------------------------------------------------------------------
template<int K>
__global__ __launch_bounds__(256)
void csr_mean_f32(const float* __restrict__ h, const int* __restrict__ esrc,
                  const int* __restrict__ ptr, half_t* __restrict__ mean, int n)
{
    constexpr int TPN = K / 4;
    constexpr int NPB = 256 / TPN;
    const int node = blockIdx.x * NPB + threadIdx.x / TPN;
    const int lane = threadIdx.x % TPN;
    if (node >= n) return;
    const int beg = ptr[node], end = ptr[node + 1];
    float4 acc = make_float4(0.f, 0.f, 0.f, 0.f);
    for (int p = beg; p < end; ++p) {
        const int s = esrc[p];
        const float4 v = *reinterpret_cast<const float4*>(h + (size_t)s * K + (size_t)lane * 4);
        acc.x += v.x; acc.y += v.y; acc.z += v.z; acc.w += v.w;
    }
    const float r = 1.0f / fmaxf((float)(end - beg), 1.0f);
    f16x4 o;
    o[0] = (half_t)(acc.x * r); o[1] = (half_t)(acc.y * r);
    o[2] = (half_t)(acc.z * r); o[3] = (half_t)(acc.w * r);
    *reinterpret_cast<f16x4*>(mean + (size_t)node * K + (size_t)lane * 4) = o;
}

template<int K>
__global__ __launch_bounds__(256)
void csr_mean_f16(const half_t* __restrict__ h, const int* __restrict__ esrc,
                  const int* __restrict__ ptr, half_t* __restrict__ mean, int n)
{
    constexpr int TPN = K / 8;
    constexpr int NPB = 256 / TPN;
    const int node = blockIdx.x * NPB + threadIdx.x / TPN;
    const int lane = threadIdx.x % TPN;
    if (node >= n) return;
    const int beg = ptr[node], end = ptr[node + 1];
    float acc[8] = {};
    for (int p = beg; p < end; ++p) {
        const int s = esrc[p];
        const f16x8 v = *reinterpret_cast<const f16x8*>(h + (size_t)s * K + (size_t)lane * 8);
        #pragma unroll
        for (int i = 0; i < 8; ++i) acc[i] += (float)v[i];
    }
    const float r = 1.0f / fmaxf((float)(end - beg), 1.0f);
    f16x8 o;
    #pragma unroll
    for (int i = 0; i < 8; ++i) o[i] = (half_t)(acc[i] * r);
    *reinterpret_cast<f16x8*>(mean + (size_t)node * K + (size_t)lane * 8) = o;
}

// ---------------------------------------------------------------------------
// MFMA GEMM: C[M x 256] = A @ Ws^T' (+ Mean @ Wn^T') + bias, optional ReLU.
// A, Mean: fp16 row-major [M][K]. WsT/WnT: fp16 [256][K] (pre-transposed).
// Tile: BM=64, BN=256 (full width), BK=32. 256 threads = 4 waves; wave w owns
// cols [64w, 64w+64): 4x4 fragments of 16x16, mfma_f32_16x16x32_f16.
// ---------------------------------------------------------------------------
#define GBM 64
#define GBK 32
#define LPAD 40   // halfs per LDS row (80 B) -> conflict-free b128

template<bool HAS_MEAN, bool RELU, bool OUT_F16>
__global__ __launch_bounds__(256)
void mfma_gemm(const half_t* __restrict__ A,
               const half_t* __restrict__ Mn,
               const half_t* __restrict__ WsT,
               const half_t* __restrict__ WnT,
               const float* __restrict__ bias,
               void* __restrict__ Cout,
               int M, int K)
{
    __shared__ half_t sA[GBM][LPAD];
    __shared__ half_t sB[256][LPAD];

    const int tid  = threadIdx.x;
    const int wid  = tid >> 6;
    const int lane = tid & 63;
    const int bm   = blockIdx.x * GBM;

    f32x4 acc[4][4] = {};   // [m][n]

    const int npass = HAS_MEAN ? 2 : 1;
    for (int pass = 0; pass < npass; ++pass) {
        const half_t* __restrict__ Ap = pass ? Mn : A;
        const half_t* __restrict__ Wp = pass ? WnT : WsT;

        for (int k0 = 0; k0 < K; k0 += GBK) {
            // stage A tile [64][32]
            {
                const int row = tid >> 2;
                const int kq  = (tid & 3) * 8;
                f16x8 v = {};
                if (bm + row < M)
                    v = *reinterpret_cast<const f16x8*>(Ap + (size_t)(bm + row) * K + k0 + kq);
                *reinterpret_cast<f16x8*>(&sA[row][kq]) = v;
            }
            // stage B tile [256][32] from WT row-major
            {
                const int kq = (tid & 3) * 8;
                const int r0 = tid >> 2;
                #pragma unroll
                for (int j = 0; j < 4; ++j) {
                    const int row = r0 + 64 * j;
                    const f16x8 v = *reinterpret_cast<const f16x8*>(Wp + (size_t)row * K + k0 + kq);
                    *reinterpret_cast<f16x8*>(&sB[row][kq]) = v;
                }
            }
            __syncthreads();

            const int lrow = lane & 15;
            const int koff = (lane >> 4) * 8;
            f16x8 af[4], bf[4];
            #pragma unroll
            for (int m = 0; m < 4; ++m)
                af[m] = *reinterpret_cast<const f16x8*>(&sA[m * 16 + lrow][koff]);
            #pragma unroll
            for (int n = 0; n < 4; ++n)
                bf[n] = *reinterpret_cast<const f16x8*>(&sB[wid * 64 + n * 16 + lrow][koff]);
            #pragma unroll
            for (int m = 0; m < 4; ++m)
                #pragma unroll
                for (int n = 0; n < 4; ++n)
                    acc[m][n] = __builtin_amdgcn_mfma_f32_16x16x32_f16(af[m], bf[n], acc[m][n], 0, 0, 0);
            __syncthreads();
        }
    }

    // epilogue: D row=(lane>>4)*4+r, col=lane&15 within each 16x16 fragment
    const int lcol = lane & 15;
    const int rgrp = lane >> 4;
    #pragma unroll
    for (int m = 0; m < 4; ++m) {
        #pragma unroll
        for (int n = 0; n < 4; ++n) {
            const int col = wid * 64 + n * 16 + lcol;
            const float bv = bias[col];
            #pragma unroll
            for (int r = 0; r < 4; ++r) {
                const int row = bm + m * 16 + rgrp * 4 + r;
                if (row >= M) continue;
                float v = acc[m][n][r] + bv;
                if (RELU) v = fmaxf(v, 0.0f);
                if (OUT_F16) ((half_t*)Cout)[(size_t)row * 256 + col] = (half_t)v;
                else         ((float*)Cout)[(size_t)row * 256 + col] = v;
            }
        }
    }
}

static constexpr size_t align256(size_t x) { return (x + 255) & ~(size_t)255; }

extern "C" void kernel_launch(void* const* d_in, const int* in_sizes, int n_in,
                              void* d_out, int out_size, void* d_ws, size_t ws_size,
                              hipStream_t stream)
{
    const float* x    = (const float*)d_in[0];
    const int*  src0  = (const int*)d_in[1];
    const int*  dst0  = (const int*)d_in[2];
    const int*  src1  = (const int*)d_in[3];
    const int*  dst1  = (const int*)d_in[4];
    const int*  src2  = (const int*)d_in[5];
    const int*  dst2  = (const int*)d_in[6];
    const float* Ws0  = (const float*)d_in[7];
    const float* Wn0  = (const float*)d_in[8];
    const float* b0   = (const float*)d_in[9];
    const float* Ws1  = (const float*)d_in[10];
    const float* Wn1  = (const float*)d_in[11];
    const float* b1   = (const float*)d_in[12];
    const float* Ws2  = (const float*)d_in[13];
    const float* Wn2  = (const float*)d_in[14];
    const float* b2   = (const float*)d_in[15];
    const float* W_fc = (const float*)d_in[16];
    const float* b_fc = (const float*)d_in[17];
    float* out = (float*)d_out;

    // ---- workspace layout ----
    char* ws = (char*)d_ws;
    size_t off = 0;
    const size_t cntA_off = off; off = align256(off + (size_t)(N1 + N2 + N3) * 4); // zeroed as one region
    const size_t ptr0_off = off; off = align256(off + (size_t)(N1 + 1) * 4);
    const size_t ptr1_off = off; off = align256(off + (size_t)(N2 + 1) * 4);
    const size_t ptr2_off = off; off = align256(off + (size_t)(N3 + 1) * 4);
    const size_t cur0_off = off; off = align256(off + (size_t)N1 * 4);
    const size_t cur1_off = off; off = align256(off + (size_t)N2 * 4);
    const size_t cur2_off = off; off = align256(off + (size_t)N3 * 4);
    const size_t es0_off  = off; off = align256(off + (size_t)E0 * 4);
    const size_t es1_off  = off; off = align256(off + (size_t)E1 * 4);
    const size_t es2_off  = off; off = align256(off + (size_t)E2 * 4);
    const size_t xh_off   = off; off = align256(off + (size_t)N1 * D_IN * 2);
    const size_t mean_off = off; off = align256(off + (size_t)N1 * D_IN * 2);
    const size_t h0_off   = off; off = align256(off + (size_t)N1 * D_H * 2);
    const size_t h1_off   = off; off = align256(off + (size_t)N2 * D_H * 2);
    const size_t h2_off   = off; off = align256(off + (size_t)N3 * D_H * 2);
    const size_t wt0_off  = off; off = align256(off + (size_t)D_IN * D_H * 2);  // WsT0
    const size_t wt1_off  = off; off = align256(off + (size_t)D_IN * D_H * 2);  // WnT0
    const size_t wt2_off  = off; off = align256(off + (size_t)D_H * D_H * 2);   // WsT1
    const size_t wt3_off  = off; off = align256(off + (size_t)D_H * D_H * 2);   // WnT1
    const size_t wt4_off  = off; off = align256(off + (size_t)D_H * D_H * 2);   // WsT2
    const size_t wt5_off  = off; off = align256(off + (size_t)D_H * D_H * 2);   // WnT2
    const size_t wt6_off  = off; off = align256(off + (size_t)D_H * D_H * 2);   // WfcT

    int* cnt0 = (int*)(ws + cntA_off);
    int* cnt1 = cnt0 + N1;
    int* cnt2 = cnt1 + N2;
    int* ptr0 = (int*)(ws + ptr0_off);
    int* ptr1 = (int*)(ws + ptr1_off);
    int* ptr2 = (int*)(ws + ptr2_off);
    int* cur0 = (int*)(ws + cur0_off);
    int* cur1 = (int*)(ws + cur1_off);
    int* cur2 = (int*)(ws + cur2_off);
    int* es0  = (int*)(ws + es0_off);
    int* es1  = (int*)(ws + es1_off);
    int* es2  = (int*)(ws + es2_off);
    half_t* xh   = (half_t*)(ws + xh_off);
    half_t* mean = (half_t*)(ws + mean_off);
    half_t* h0   = (half_t*)(ws + h0_off);
    half_t* h1   = (half_t*)(ws + h1_off);
    half_t* h2   = (half_t*)(ws + h2_off);
    half_t* WsT0 = (half_t*)(ws + wt0_off);
    half_t* WnT0 = (half_t*)(ws + wt1_off);
    half_t* WsT1 = (half_t*)(ws + wt2_off);
    half_t* WnT1 = (half_t*)(ws + wt3_off);
    half_t* WsT2 = (half_t*)(ws + wt4_off);
    half_t* WnT2 = (half_t*)(ws + wt5_off);
    half_t* WfcT = (half_t*)(ws + wt6_off);

    // ---- CSR build (all layers) + conversions ----
    hipMemsetAsync(cnt0, 0, (size_t)(N1 + N2 + N3) * 4, stream);
    {
        const int tot = E0 + E1 + E2;
        hist3_kernel<<<(tot + 255) / 256, 256, 0, stream>>>(dst0, dst1, dst2, cnt0, cnt1, cnt2);
        scan3_kernel<<<3, 1024, 0, stream>>>(cnt0, ptr0, cur0, cnt1, ptr1, cur1, cnt2, ptr2, cur2);
        fill3_kernel<<<(tot + 255) / 256, 256, 0, stream>>>(
            src0, dst0, src1, dst1, src2, dst2, cur0, cur1, cur2, es0, es1, es2);
    }
    wconv_kernel<<<2304, 256, 0, stream>>>(Ws0, Wn0, Ws1, Wn1, Ws2, Wn2, W_fc,
                                           WsT0, WnT0, WsT1, WnT1, WsT2, WnT2, WfcT);
    {
        const int n8 = N1 * D_IN / 8;   // 1.6M
        xconv_kernel<<<(n8 + 255) / 256, 256, 0, stream>>>(x, xh, n8);
    }

    // ---- layer 0 ----
    {
        constexpr int NPB = 256 / (D_IN / 4);   // 2
        csr_mean_f32<D_IN><<<(N1 + NPB - 1) / NPB, 256, 0, stream>>>(x, es0, ptr0, mean, N1);
        mfma_gemm<true, true, true><<<(N1 + GBM - 1) / GBM, 256, 0, stream>>>(
            xh, mean, WsT0, WnT0, b0, h0, N1, D_IN);
    }
    // ---- layer 1 ----
    {
        constexpr int NPB = 256 / (D_H / 8);    // 8
        csr_mean_f16<D_H><<<(N2 + NPB - 1) / NPB, 256, 0, stream>>>(h0, es1, ptr1, mean, N2);
        mfma_gemm<true, true, true><<<(N2 + GBM - 1) / GBM, 256, 0, stream>>>(
            h0, mean, WsT1, WnT1, b1, h1, N2, D_H);
    }
    // ---- layer 2 (no relu) ----
    {
        constexpr int NPB = 256 / (D_H / 8);
        csr_mean_f16<D_H><<<(N3 + NPB - 1) / NPB, 256, 0, stream>>>(h1, es2, ptr2, mean, N3);
        mfma_gemm<true, false, true><<<(N3 + GBM - 1) / GBM, 256, 0, stream>>>(
            h1, mean, WsT2, WnT2, b2, h2, N3, D_H);
    }
    // ---- final FC (fp32 out) ----
    mfma_gemm<false, false, false><<<(N3 + GBM - 1) / GBM, 256, 0, stream>>>(
        h2, nullptr, WfcT, nullptr, b_fc, out, N3, D_H);
}

// Round 4
// 347.559 us; speedup vs baseline: 9.8884x; 1.0525x over previous
//
#include <hip/hip_runtime.h>
#include <hip/hip_bf16.h>
#include <cstddef>
#include <cstdint>

// Problem constants
#define N0 100000
#define N1 25000
#define N2 6250
#define N3 1600
#define DEG 16
#define D_IN 512
#define D_H 256

#define E0 (N1*DEG)   // 400000
#define E1 (N2*DEG)   // 100000
#define E2 (N3*DEG)   // 25600

typedef _Float16 half_t;
typedef __attribute__((ext_vector_type(8))) _Float16 f16x8;
typedef __attribute__((ext_vector_type(4))) _Float16 f16x4;
typedef __attribute__((ext_vector_type(4))) float f32x4;

// ---------------------------------------------------------------------------
// Fused CSR build (all 3 layers): hist -> scan -> fill
// ---------------------------------------------------------------------------
__global__ void hist3_kernel(const int* __restrict__ d0, const int* __restrict__ d1,
                             const int* __restrict__ d2,
                             int* __restrict__ c0, int* __restrict__ c1, int* __restrict__ c2)
{
    const int i = blockIdx.x * 256 + threadIdx.x;
    if (i < E0)            atomicAdd(&c0[d0[i]], 1);
    else if (i < E0 + E1)  atomicAdd(&c1[d1[i - E0]], 1);
    else if (i < E0 + E1 + E2) atomicAdd(&c2[d2[i - E0 - E1]], 1);
}

__global__ void fill3_kernel(const int* __restrict__ s0, const int* __restrict__ d0,
                             const int* __restrict__ s1, const int* __restrict__ d1,
                             const int* __restrict__ s2, const int* __restrict__ d2,
                             int* __restrict__ u0, int* __restrict__ u1, int* __restrict__ u2,
                             int* __restrict__ e0, int* __restrict__ e1, int* __restrict__ e2)
{
    const int i = blockIdx.x * 256 + threadIdx.x;
    if (i < E0) {
        const int p = atomicAdd(&u0[d0[i]], 1); e0[p] = s0[i];
    } else if (i < E0 + E1) {
        const int j = i - E0;
        const int p = atomicAdd(&u1[d1[j]], 1); e1[p] = s1[j];
    } else if (i < E0 + E1 + E2) {
        const int j = i - E0 - E1;
        const int p = atomicAdd(&u2[d2[j]], 1); e2[p] = s2[j];
    }
}

// 3-phase block scan; block b handles layer b. Writes ptr[0..n] and cursor[0..n).
__global__ __launch_bounds__(1024)
void scan3_kernel(const int* __restrict__ c0, int* __restrict__ p0, int* __restrict__ u0,
                  const int* __restrict__ c1, int* __restrict__ p1, int* __restrict__ u1,
                  const int* __restrict__ c2, int* __restrict__ p2, int* __restrict__ u2)
{
    const int b = blockIdx.x;
    const int* cnt = (b == 0) ? c0 : (b == 1) ? c1 : c2;
    int* ptr = (b == 0) ? p0 : (b == 1) ? p1 : p2;
    int* cur = (b == 0) ? u0 : (b == 1) ? u1 : u2;
    const int n = (b == 0) ? N1 : (b == 1) ? N2 : N3;

    const int t = threadIdx.x;
    const int chunk = (n + 1023) >> 10;
    const int beg = t * chunk;
    const int end = min(n, beg + chunk);

    int sum = 0;
    for (int i = beg; i < end; ++i) sum += cnt[i];

    const int lane = t & 63, wid = t >> 6;
    int inc = sum;
    #pragma unroll
    for (int d = 1; d < 64; d <<= 1) {
        int u = __shfl_up(inc, d, 64);
        if (lane >= d) inc += u;
    }
    __shared__ int wtot[16];
    __shared__ int total_s;
    if (lane == 63) wtot[wid] = inc;
    __syncthreads();
    if (wid == 0) {
        int w = (lane < 16) ? wtot[lane] : 0;
        int ws = w;
        #pragma unroll
        for (int d = 1; d < 16; d <<= 1) {
            int u = __shfl_up(ws, d, 64);
            if (lane >= d) ws += u;
        }
        if (lane < 16) wtot[lane] = ws - w;   // exclusive wave offset
        if (lane == 15) total_s = ws;         // block total
    }
    __syncthreads();
    int run = (inc - sum) + wtot[wid];
    for (int i = beg; i < end; ++i) {
        ptr[i] = run; cur[i] = run;
        run += cnt[i];
    }
    if (t == 0) ptr[n] = total_s;
}

// ---------------------------------------------------------------------------
// Conversions: fp32 -> fp16
// ---------------------------------------------------------------------------
__global__ __launch_bounds__(256)
void xconv_kernel(const float* __restrict__ x, half_t* __restrict__ xh, int n8)
{
    const int id = blockIdx.x * 256 + threadIdx.x;
    if (id >= n8) return;
    const float4* p = reinterpret_cast<const float4*>(x) + (size_t)id * 2;
    const float4 a = p[0], b = p[1];
    f16x8 o;
    o[0] = (half_t)a.x; o[1] = (half_t)a.y; o[2] = (half_t)a.z; o[3] = (half_t)a.w;
    o[4] = (half_t)b.x; o[5] = (half_t)b.y; o[6] = (half_t)b.z; o[7] = (half_t)b.w;
    *(reinterpret_cast<f16x8*>(xh) + id) = o;
}

// transpose+convert 7 weight matrices [K][256] fp32 -> [256][K] fp16
__global__ __launch_bounds__(256)
void wconv_kernel(const float* s0, const float* s1, const float* s2, const float* s3,
                  const float* s4, const float* s5, const float* s6,
                  half_t* t0, half_t* t1, half_t* t2, half_t* t3,
                  half_t* t4, half_t* t5, half_t* t6)
{
    const int id = blockIdx.x * 256 + threadIdx.x;
    const float* src; half_t* dst; int kb; int e;
    if (id < 131072)      { src = s0; dst = t0; kb = 9; e = id; }
    else if (id < 262144) { src = s1; dst = t1; kb = 9; e = id - 131072; }
    else if (id < 327680) { src = s2; dst = t2; kb = 8; e = id - 262144; }
    else if (id < 393216) { src = s3; dst = t3; kb = 8; e = id - 327680; }
    else if (id < 458752) { src = s4; dst = t4; kb = 8; e = id - 393216; }
    else if (id < 524288) { src = s5; dst = t5; kb = 8; e = id - 458752; }
    else if (id < 589824) { src = s6; dst = t6; kb = 8; e = id - 524288; }
    else return;
    const int K = 1 << kb;
    const int nn = e >> kb, k = e & (K - 1);
    dst[((size_t)nn << kb) + k] = (half_t)src[(size_t)k * 256 + nn];
}

// ---------------------------------------------------------------------------
// CSR gather-mean, fp16 inputs, fp32 accumulate, fp16 out.
// TPN = K/8 lanes per node (one f16x8 each).
// ---------------------------------------------------------------------------
template<int K>
__global__ __launch_bounds__(256)
void csr_mean_f16(const half_t* __restrict__ h, const int* __restrict__ esrc,
                  const int* __restrict__ ptr, half_t* __restrict__ mean, int n)
{
    constexpr int TPN = K / 8;
    constexpr int NPB = 256 / TPN;
    const int node = blockIdx.x * NPB + threadIdx.x / TPN;
    const int lane = threadIdx.x % TPN;
    if (node >= n) return;
    const int beg = ptr[node], end = ptr[node + 1];
    float acc[8] = {};
    for (int p = beg; p < end; ++p) {
        const int s = esrc[p];
        const f16x8 v = *reinterpret_cast<const f16x8*>(h + (size_t)s * K + (size_t)lane * 8);
        #pragma unroll
        for (int i = 0; i < 8; ++i) acc[i] += (float)v[i];
    }
    const float r = 1.0f / fmaxf((float)(end - beg), 1.0f);
    f16x8 o;
    #pragma unroll
    for (int i = 0; i < 8; ++i) o[i] = (half_t)(acc[i] * r);
    *reinterpret_cast<f16x8*>(mean + (size_t)node * K + (size_t)lane * 8) = o;
}

// ---------------------------------------------------------------------------
// MFMA GEMM: C[M x 256] = A @ Ws^T' (+ Mean @ Wn^T') + bias, optional ReLU.
// A, Mean: fp16 row-major [M][K]. WsT/WnT: fp16 [256][K] (pre-transposed).
// Tile: BM=64, BN=256 (full width), BK=32. 256 threads = 4 waves; wave w owns
// cols [64w, 64w+64): 4x4 fragments of 16x16, mfma_f32_16x16x32_f16.
// ---------------------------------------------------------------------------
#define GBM 64
#define GBK 32
#define LPAD 40   // halfs per LDS row (80 B) -> conflict-free b128

template<bool HAS_MEAN, bool RELU, bool OUT_F16>
__global__ __launch_bounds__(256)
void mfma_gemm(const half_t* __restrict__ A,
               const half_t* __restrict__ Mn,
               const half_t* __restrict__ WsT,
               const half_t* __restrict__ WnT,
               const float* __restrict__ bias,
               void* __restrict__ Cout,
               int M, int K)
{
    __shared__ half_t sA[GBM][LPAD];
    __shared__ half_t sB[256][LPAD];

    const int tid  = threadIdx.x;
    const int wid  = tid >> 6;
    const int lane = tid & 63;
    const int bm   = blockIdx.x * GBM;

    f32x4 acc[4][4] = {};   // [m][n]

    const int npass = HAS_MEAN ? 2 : 1;
    for (int pass = 0; pass < npass; ++pass) {
        const half_t* __restrict__ Ap = pass ? Mn : A;
        const half_t* __restrict__ Wp = pass ? WnT : WsT;

        for (int k0 = 0; k0 < K; k0 += GBK) {
            // stage A tile [64][32]
            {
                const int row = tid >> 2;
                const int kq  = (tid & 3) * 8;
                f16x8 v = {};
                if (bm + row < M)
                    v = *reinterpret_cast<const f16x8*>(Ap + (size_t)(bm + row) * K + k0 + kq);
                *reinterpret_cast<f16x8*>(&sA[row][kq]) = v;
            }
            // stage B tile [256][32] from WT row-major
            {
                const int kq = (tid & 3) * 8;
                const int r0 = tid >> 2;
                #pragma unroll
                for (int j = 0; j < 4; ++j) {
                    const int row = r0 + 64 * j;
                    const f16x8 v = *reinterpret_cast<const f16x8*>(Wp + (size_t)row * K + k0 + kq);
                    *reinterpret_cast<f16x8*>(&sB[row][kq]) = v;
                }
            }
            __syncthreads();

            const int lrow = lane & 15;
            const int koff = (lane >> 4) * 8;
            f16x8 af[4], bf[4];
            #pragma unroll
            for (int m = 0; m < 4; ++m)
                af[m] = *reinterpret_cast<const f16x8*>(&sA[m * 16 + lrow][koff]);
            #pragma unroll
            for (int n = 0; n < 4; ++n)
                bf[n] = *reinterpret_cast<const f16x8*>(&sB[wid * 64 + n * 16 + lrow][koff]);
            #pragma unroll
            for (int m = 0; m < 4; ++m)
                #pragma unroll
                for (int n = 0; n < 4; ++n)
                    acc[m][n] = __builtin_amdgcn_mfma_f32_16x16x32_f16(af[m], bf[n], acc[m][n], 0, 0, 0);
            __syncthreads();
        }
    }

    // epilogue: D row=(lane>>4)*4+r, col=lane&15 within each 16x16 fragment
    const int lcol = lane & 15;
    const int rgrp = lane >> 4;
    #pragma unroll
    for (int m = 0; m < 4; ++m) {
        #pragma unroll
        for (int n = 0; n < 4; ++n) {
            const int col = wid * 64 + n * 16 + lcol;
            const float bv = bias[col];
            #pragma unroll
            for (int r = 0; r < 4; ++r) {
                const int row = bm + m * 16 + rgrp * 4 + r;
                if (row >= M) continue;
                float v = acc[m][n][r] + bv;
                if (RELU) v = fmaxf(v, 0.0f);
                if (OUT_F16) ((half_t*)Cout)[(size_t)row * 256 + col] = (half_t)v;
                else         ((float*)Cout)[(size_t)row * 256 + col] = v;
            }
        }
    }
}

static constexpr size_t align256(size_t x) { return (x + 255) & ~(size_t)255; }

extern "C" void kernel_launch(void* const* d_in, const int* in_sizes, int n_in,
                              void* d_out, int out_size, void* d_ws, size_t ws_size,
                              hipStream_t stream)
{
    const float* x    = (const float*)d_in[0];
    const int*  src0  = (const int*)d_in[1];
    const int*  dst0  = (const int*)d_in[2];
    const int*  src1  = (const int*)d_in[3];
    const int*  dst1  = (const int*)d_in[4];
    const int*  src2  = (const int*)d_in[5];
    const int*  dst2  = (const int*)d_in[6];
    const float* Ws0  = (const float*)d_in[7];
    const float* Wn0  = (const float*)d_in[8];
    const float* b0   = (const float*)d_in[9];
    const float* Ws1  = (const float*)d_in[10];
    const float* Wn1  = (const float*)d_in[11];
    const float* b1   = (const float*)d_in[12];
    const float* Ws2  = (const float*)d_in[13];
    const float* Wn2  = (const float*)d_in[14];
    const float* b2   = (const float*)d_in[15];
    const float* W_fc = (const float*)d_in[16];
    const float* b_fc = (const float*)d_in[17];
    float* out = (float*)d_out;

    // ---- workspace layout ----
    char* ws = (char*)d_ws;
    size_t off = 0;
    const size_t cntA_off = off; off = align256(off + (size_t)(N1 + N2 + N3) * 4); // zeroed as one region
    const size_t ptr0_off = off; off = align256(off + (size_t)(N1 + 1) * 4);
    const size_t ptr1_off = off; off = align256(off + (size_t)(N2 + 1) * 4);
    const size_t ptr2_off = off; off = align256(off + (size_t)(N3 + 1) * 4);
    const size_t cur0_off = off; off = align256(off + (size_t)N1 * 4);
    const size_t cur1_off = off; off = align256(off + (size_t)N2 * 4);
    const size_t cur2_off = off; off = align256(off + (size_t)N3 * 4);
    const size_t es0_off  = off; off = align256(off + (size_t)E0 * 4);
    const size_t es1_off  = off; off = align256(off + (size_t)E1 * 4);
    const size_t es2_off  = off; off = align256(off + (size_t)E2 * 4);
    const size_t xh_off   = off; off = align256(off + (size_t)N0 * D_IN * 2);   // FULL x table fp16
    const size_t mean_off = off; off = align256(off + (size_t)N1 * D_IN * 2);
    const size_t h0_off   = off; off = align256(off + (size_t)N1 * D_H * 2);
    const size_t h1_off   = off; off = align256(off + (size_t)N2 * D_H * 2);
    const size_t h2_off   = off; off = align256(off + (size_t)N3 * D_H * 2);
    const size_t wt0_off  = off; off = align256(off + (size_t)D_IN * D_H * 2);  // WsT0
    const size_t wt1_off  = off; off = align256(off + (size_t)D_IN * D_H * 2);  // WnT0
    const size_t wt2_off  = off; off = align256(off + (size_t)D_H * D_H * 2);   // WsT1
    const size_t wt3_off  = off; off = align256(off + (size_t)D_H * D_H * 2);   // WnT1
    const size_t wt4_off  = off; off = align256(off + (size_t)D_H * D_H * 2);   // WsT2
    const size_t wt5_off  = off; off = align256(off + (size_t)D_H * D_H * 2);   // WnT2
    const size_t wt6_off  = off; off = align256(off + (size_t)D_H * D_H * 2);   // WfcT

    int* cnt0 = (int*)(ws + cntA_off);
    int* cnt1 = cnt0 + N1;
    int* cnt2 = cnt1 + N2;
    int* ptr0 = (int*)(ws + ptr0_off);
    int* ptr1 = (int*)(ws + ptr1_off);
    int* ptr2 = (int*)(ws + ptr2_off);
    int* cur0 = (int*)(ws + cur0_off);
    int* cur1 = (int*)(ws + cur1_off);
    int* cur2 = (int*)(ws + cur2_off);
    int* es0  = (int*)(ws + es0_off);
    int* es1  = (int*)(ws + es1_off);
    int* es2  = (int*)(ws + es2_off);
    half_t* xh   = (half_t*)(ws + xh_off);
    half_t* mean = (half_t*)(ws + mean_off);
    half_t* h0   = (half_t*)(ws + h0_off);
    half_t* h1   = (half_t*)(ws + h1_off);
    half_t* h2   = (half_t*)(ws + h2_off);
    half_t* WsT0 = (half_t*)(ws + wt0_off);
    half_t* WnT0 = (half_t*)(ws + wt1_off);
    half_t* WsT1 = (half_t*)(ws + wt2_off);
    half_t* WnT1 = (half_t*)(ws + wt3_off);
    half_t* WsT2 = (half_t*)(ws + wt4_off);
    half_t* WnT2 = (half_t*)(ws + wt5_off);
    half_t* WfcT = (half_t*)(ws + wt6_off);

    // ---- CSR build (all layers) + conversions ----
    hipMemsetAsync(cnt0, 0, (size_t)(N1 + N2 + N3) * 4, stream);
    {
        const int tot = E0 + E1 + E2;
        hist3_kernel<<<(tot + 255) / 256, 256, 0, stream>>>(dst0, dst1, dst2, cnt0, cnt1, cnt2);
        scan3_kernel<<<3, 1024, 0, stream>>>(cnt0, ptr0, cur0, cnt1, ptr1, cur1, cnt2, ptr2, cur2);
        fill3_kernel<<<(tot + 255) / 256, 256, 0, stream>>>(
            src0, dst0, src1, dst1, src2, dst2, cur0, cur1, cur2, es0, es1, es2);
    }
    wconv_kernel<<<2304, 256, 0, stream>>>(Ws0, Wn0, Ws1, Wn1, Ws2, Wn2, W_fc,
                                           WsT0, WnT0, WsT1, WnT1, WsT2, WnT2, WfcT);
    {
        const int n8 = N0 * D_IN / 8;   // 6.4M vectors: convert the FULL x table
        xconv_kernel<<<(n8 + 255) / 256, 256, 0, stream>>>(x, xh, n8);
    }

    // ---- layer 0 (gather fp16 table: L3-resident, half the traffic) ----
    {
        constexpr int NPB = 256 / (D_IN / 8);   // 4 nodes / block, 64 lanes each
        csr_mean_f16<D_IN><<<(N1 + NPB - 1) / NPB, 256, 0, stream>>>(xh, es0, ptr0, mean, N1);
        mfma_gemm<true, true, true><<<(N1 + GBM - 1) / GBM, 256, 0, stream>>>(
            xh, mean, WsT0, WnT0, b0, h0, N1, D_IN);
    }
    // ---- layer 1 ----
    {
        constexpr int NPB = 256 / (D_H / 8);    // 8
        csr_mean_f16<D_H><<<(N2 + NPB - 1) / NPB, 256, 0, stream>>>(h0, es1, ptr1, mean, N2);
        mfma_gemm<true, true, true><<<(N2 + GBM - 1) / GBM, 256, 0, stream>>>(
            h0, mean, WsT1, WnT1, b1, h1, N2, D_H);
    }
    // ---- layer 2 (no relu) ----
    {
        constexpr int NPB = 256 / (D_H / 8);
        csr_mean_f16<D_H><<<(N3 + NPB - 1) / NPB, 256, 0, stream>>>(h1, es2, ptr2, mean, N3);
        mfma_gemm<true, false, true><<<(N3 + GBM - 1) / GBM, 256, 0, stream>>>(
            h1, mean, WsT2, WnT2, b2, h2, N3, D_H);
    }
    // ---- final FC (fp32 out) ----
    mfma_gemm<false, false, false><<<(N3 + GBM - 1) / GBM, 256, 0, stream>>>(
        h2, nullptr, WfcT, nullptr, b_fc, out, N3, D_H);
}

// Round 5
// 309.101 us; speedup vs baseline: 11.1187x; 1.1244x over previous
//
#include <hip/hip_runtime.h>
#include <hip/hip_bf16.h>
#include <cstddef>
#include <cstdint>

// Problem constants
#define N0 100000
#define N1 25000
#define N2 6250
#define N3 1600
#define DEG 16
#define D_IN 512
#define D_H 256

#define E0 (N1*DEG)   // 400000
#define E1 (N2*DEG)   // 100000
#define E2 (N3*DEG)   // 25600

typedef _Float16 half_t;
typedef __attribute__((ext_vector_type(8))) _Float16 f16x8;
typedef __attribute__((ext_vector_type(4))) float f32x4;

// block-range partition of the fused conversion kernel
#define XB 25000                        // xconv blocks: N0*512/8/256
#define WB 2304                         // wconv blocks: 589824/256
#define HB (((E0+E1+E2) + 255) / 256)   // hist blocks:  2054

// ---------------------------------------------------------------------------
// Fused: xconv (fp32 x -> fp16 xh) | wconv (7 weights transpose+fp16) | hist3
// ---------------------------------------------------------------------------
__global__ __launch_bounds__(256)
void mega_conv_kernel(const float* __restrict__ x, half_t* __restrict__ xh,
                      const float* s0, const float* s1, const float* s2, const float* s3,
                      const float* s4, const float* s5, const float* s6,
                      half_t* t0, half_t* t1, half_t* t2, half_t* t3,
                      half_t* t4, half_t* t5, half_t* t6,
                      const int* __restrict__ d0, const int* __restrict__ d1,
                      const int* __restrict__ d2,
                      int* __restrict__ c0, int* __restrict__ c1, int* __restrict__ c2)
{
    const int bid = blockIdx.x;
    if (bid < XB) {
        // ---- xconv: 8 floats -> 8 halfs per thread ----
        const int id = bid * 256 + threadIdx.x;          // < 6.4M
        const float4* p = reinterpret_cast<const float4*>(x) + (size_t)id * 2;
        const float4 a = p[0], b = p[1];
        f16x8 o;
        o[0] = (half_t)a.x; o[1] = (half_t)a.y; o[2] = (half_t)a.z; o[3] = (half_t)a.w;
        o[4] = (half_t)b.x; o[5] = (half_t)b.y; o[6] = (half_t)b.z; o[7] = (half_t)b.w;
        *(reinterpret_cast<f16x8*>(xh) + id) = o;
    } else if (bid < XB + WB) {
        // ---- wconv: transpose+convert [K][256] fp32 -> [256][K] fp16 ----
        const int id = (bid - XB) * 256 + threadIdx.x;
        const float* src; half_t* dst; int kb; int e;
        if (id < 131072)      { src = s0; dst = t0; kb = 9; e = id; }
        else if (id < 262144) { src = s1; dst = t1; kb = 9; e = id - 131072; }
        else if (id < 327680) { src = s2; dst = t2; kb = 8; e = id - 262144; }
        else if (id < 393216) { src = s3; dst = t3; kb = 8; e = id - 327680; }
        else if (id < 458752) { src = s4; dst = t4; kb = 8; e = id - 393216; }
        else if (id < 524288) { src = s5; dst = t5; kb = 8; e = id - 458752; }
        else if (id < 589824) { src = s6; dst = t6; kb = 8; e = id - 524288; }
        else return;
        const int K = 1 << kb;
        const int nn = e >> kb, k = e & (K - 1);
        dst[((size_t)nn << kb) + k] = (half_t)src[(size_t)k * 256 + nn];
    } else {
        // ---- hist3 ----
        const int i = (bid - XB - WB) * 256 + threadIdx.x;
        if (i < E0)                atomicAdd(&c0[d0[i]], 1);
        else if (i < E0 + E1)      atomicAdd(&c1[d1[i - E0]], 1);
        else if (i < E0 + E1 + E2) atomicAdd(&c2[d2[i - E0 - E1]], 1);
    }
}

// ---------------------------------------------------------------------------
// fill3: scatter src values into dst-ordered buckets
// ---------------------------------------------------------------------------
__global__ void fill3_kernel(const int* __restrict__ s0, const int* __restrict__ d0,
                             const int* __restrict__ s1, const int* __restrict__ d1,
                             const int* __restrict__ s2, const int* __restrict__ d2,
                             int* __restrict__ u0, int* __restrict__ u1, int* __restrict__ u2,
                             int* __restrict__ e0, int* __restrict__ e1, int* __restrict__ e2)
{
    const int i = blockIdx.x * 256 + threadIdx.x;
    if (i < E0) {
        const int p = atomicAdd(&u0[d0[i]], 1); e0[p] = s0[i];
    } else if (i < E0 + E1) {
        const int j = i - E0;
        const int p = atomicAdd(&u1[d1[j]], 1); e1[p] = s1[j];
    } else if (i < E0 + E1 + E2) {
        const int j = i - E0 - E1;
        const int p = atomicAdd(&u2[d2[j]], 1); e2[p] = s2[j];
    }
}

// 3-phase block scan; block b handles layer b. Writes ptr[0..n] and cursor[0..n).
__global__ __launch_bounds__(1024)
void scan3_kernel(const int* __restrict__ c0, int* __restrict__ p0, int* __restrict__ u0,
                  const int* __restrict__ c1, int* __restrict__ p1, int* __restrict__ u1,
                  const int* __restrict__ c2, int* __restrict__ p2, int* __restrict__ u2)
{
    const int b = blockIdx.x;
    const int* cnt = (b == 0) ? c0 : (b == 1) ? c1 : c2;
    int* ptr = (b == 0) ? p0 : (b == 1) ? p1 : p2;
    int* cur = (b == 0) ? u0 : (b == 1) ? u1 : u2;
    const int n = (b == 0) ? N1 : (b == 1) ? N2 : N3;

    const int t = threadIdx.x;
    const int chunk = (n + 1023) >> 10;
    const int beg = t * chunk;
    const int end = min(n, beg + chunk);

    int sum = 0;
    for (int i = beg; i < end; ++i) sum += cnt[i];

    const int lane = t & 63, wid = t >> 6;
    int inc = sum;
    #pragma unroll
    for (int d = 1; d < 64; d <<= 1) {
        int u = __shfl_up(inc, d, 64);
        if (lane >= d) inc += u;
    }
    __shared__ int wtot[16];
    __shared__ int total_s;
    if (lane == 63) wtot[wid] = inc;
    __syncthreads();
    if (wid == 0) {
        int w = (lane < 16) ? wtot[lane] : 0;
        int ws = w;
        #pragma unroll
        for (int d = 1; d < 16; d <<= 1) {
            int u = __shfl_up(ws, d, 64);
            if (lane >= d) ws += u;
        }
        if (lane < 16) wtot[lane] = ws - w;   // exclusive wave offset
        if (lane == 15) total_s = ws;         // block total
    }
    __syncthreads();
    int run = (inc - sum) + wtot[wid];
    for (int i = beg; i < end; ++i) {
        ptr[i] = run; cur[i] = run;
        run += cnt[i];
    }
    if (t == 0) ptr[n] = total_s;
}

// ---------------------------------------------------------------------------
// CSR gather-mean, fp16 in, fp32 accumulate, fp16 out.
// TPN = K/8 lanes per node. Indices loaded lane-parallel, broadcast via shfl;
// row loads unrolled x4 for MLP.
// ---------------------------------------------------------------------------
template<int K>
__global__ __launch_bounds__(256)
void csr_mean_f16(const half_t* __restrict__ h, const int* __restrict__ esrc,
                  const int* __restrict__ ptr, half_t* __restrict__ mean, int n)
{
    constexpr int TPN = K / 8;
    constexpr int NPB = 256 / TPN;
    const int node = blockIdx.x * NPB + threadIdx.x / TPN;
    const int lane = threadIdx.x % TPN;
    if (node >= n) return;
    const int beg = ptr[node], end = ptr[node + 1];
    float acc[8] = {};
    for (int base = beg; base < end; base += TPN) {
        const int rem = end - base;
        const int cnt = (rem < TPN) ? rem : TPN;
        const int myidx = (lane < cnt) ? esrc[base + lane] : 0;
        int j = 0;
        for (; j + 3 < cnt; j += 4) {
            const int a0 = __shfl(myidx, j + 0, TPN);
            const int a1 = __shfl(myidx, j + 1, TPN);
            const int a2 = __shfl(myidx, j + 2, TPN);
            const int a3 = __shfl(myidx, j + 3, TPN);
            const f16x8 v0 = *reinterpret_cast<const f16x8*>(h + (size_t)a0 * K + (size_t)lane * 8);
            const f16x8 v1 = *reinterpret_cast<const f16x8*>(h + (size_t)a1 * K + (size_t)lane * 8);
            const f16x8 v2 = *reinterpret_cast<const f16x8*>(h + (size_t)a2 * K + (size_t)lane * 8);
            const f16x8 v3 = *reinterpret_cast<const f16x8*>(h + (size_t)a3 * K + (size_t)lane * 8);
            #pragma unroll
            for (int i = 0; i < 8; ++i) acc[i] += (float)v0[i];
            #pragma unroll
            for (int i = 0; i < 8; ++i) acc[i] += (float)v1[i];
            #pragma unroll
            for (int i = 0; i < 8; ++i) acc[i] += (float)v2[i];
            #pragma unroll
            for (int i = 0; i < 8; ++i) acc[i] += (float)v3[i];
        }
        for (; j < cnt; ++j) {
            const int a0 = __shfl(myidx, j, TPN);
            const f16x8 v0 = *reinterpret_cast<const f16x8*>(h + (size_t)a0 * K + (size_t)lane * 8);
            #pragma unroll
            for (int i = 0; i < 8; ++i) acc[i] += (float)v0[i];
        }
    }
    const float r = 1.0f / fmaxf((float)(end - beg), 1.0f);
    f16x8 o;
    #pragma unroll
    for (int i = 0; i < 8; ++i) o[i] = (half_t)(acc[i] * r);
    *reinterpret_cast<f16x8*>(mean + (size_t)node * K + (size_t)lane * 8) = o;
}

// ---------------------------------------------------------------------------
// MFMA GEMM: C[M x 256] = A @ WsT^T (+ Mean @ WnT^T) + bias, optional ReLU.
// A, Mean: fp16 [M][K]. WsT/WnT: fp16 [256][K]. Tile BM=64 x BN=256, BK=32.
// 512 threads = 8 waves; wave w owns cols [32w, 32w+32): acc 4x2 fragments.
// ---------------------------------------------------------------------------
#define GBM 64
#define GBK 32
#define LPAD 40   // halfs per LDS row (80 B) -> ~2-way (free) on b128 reads

template<bool HAS_MEAN, bool RELU, bool OUT_F16>
__global__ __launch_bounds__(512)
void mfma_gemm(const half_t* __restrict__ A,
               const half_t* __restrict__ Mn,
               const half_t* __restrict__ WsT,
               const half_t* __restrict__ WnT,
               const float* __restrict__ bias,
               void* __restrict__ Cout,
               int M, int K)
{
    __shared__ half_t sA[GBM][LPAD];
    __shared__ half_t sB[256][LPAD];

    const int tid  = threadIdx.x;
    const int wid  = tid >> 6;      // 0..7
    const int lane = tid & 63;
    const int bm   = blockIdx.x * GBM;

    f32x4 acc[4][2] = {};   // [m][n]

    const int npass = HAS_MEAN ? 2 : 1;
    for (int pass = 0; pass < npass; ++pass) {
        const half_t* __restrict__ Ap = pass ? Mn : A;
        const half_t* __restrict__ Wp = pass ? WnT : WsT;

        for (int k0 = 0; k0 < K; k0 += GBK) {
            // stage A tile [64][32]: threads 0..255, one f16x8 each
            if (tid < 256) {
                const int row = tid >> 2;
                const int kq  = (tid & 3) * 8;
                f16x8 v = {};
                if (bm + row < M)
                    v = *reinterpret_cast<const f16x8*>(Ap + (size_t)(bm + row) * K + k0 + kq);
                *reinterpret_cast<f16x8*>(&sA[row][kq]) = v;
            }
            // stage B tile [256][32]: all 512 threads, two f16x8 each
            {
                const int kq = (tid & 3) * 8;
                const int r0 = tid >> 2;    // 0..127
                #pragma unroll
                for (int j = 0; j < 2; ++j) {
                    const int row = r0 + 128 * j;
                    const f16x8 v = *reinterpret_cast<const f16x8*>(Wp + (size_t)row * K + k0 + kq);
                    *reinterpret_cast<f16x8*>(&sB[row][kq]) = v;
                }
            }
            __syncthreads();

            const int lrow = lane & 15;
            const int koff = (lane >> 4) * 8;
            f16x8 af[4], bf[2];
            #pragma unroll
            for (int m = 0; m < 4; ++m)
                af[m] = *reinterpret_cast<const f16x8*>(&sA[m * 16 + lrow][koff]);
            #pragma unroll
            for (int n = 0; n < 2; ++n)
                bf[n] = *reinterpret_cast<const f16x8*>(&sB[wid * 32 + n * 16 + lrow][koff]);
            #pragma unroll
            for (int m = 0; m < 4; ++m)
                #pragma unroll
                for (int n = 0; n < 2; ++n)
                    acc[m][n] = __builtin_amdgcn_mfma_f32_16x16x32_f16(af[m], bf[n], acc[m][n], 0, 0, 0);
            __syncthreads();
        }
    }

    // epilogue: D row=(lane>>4)*4+r, col=lane&15 within each 16x16 fragment
    const int lcol = lane & 15;
    const int rgrp = lane >> 4;
    #pragma unroll
    for (int m = 0; m < 4; ++m) {
        #pragma unroll
        for (int n = 0; n < 2; ++n) {
            const int col = wid * 32 + n * 16 + lcol;
            const float bv = bias[col];
            #pragma unroll
            for (int r = 0; r < 4; ++r) {
                const int row = bm + m * 16 + rgrp * 4 + r;
                if (row >= M) continue;
                float v = acc[m][n][r] + bv;
                if (RELU) v = fmaxf(v, 0.0f);
                if (OUT_F16) ((half_t*)Cout)[(size_t)row * 256 + col] = (half_t)v;
                else         ((float*)Cout)[(size_t)row * 256 + col] = v;
            }
        }
    }
}

static constexpr size_t align256(size_t x) { return (x + 255) & ~(size_t)255; }

extern "C" void kernel_launch(void* const* d_in, const int* in_sizes, int n_in,
                              void* d_out, int out_size, void* d_ws, size_t ws_size,
                              hipStream_t stream)
{
    const float* x    = (const float*)d_in[0];
    const int*  src0  = (const int*)d_in[1];
    const int*  dst0  = (const int*)d_in[2];
    const int*  src1  = (const int*)d_in[3];
    const int*  dst1  = (const int*)d_in[4];
    const int*  src2  = (const int*)d_in[5];
    const int*  dst2  = (const int*)d_in[6];
    const float* Ws0  = (const float*)d_in[7];
    const float* Wn0  = (const float*)d_in[8];
    const float* b0   = (const float*)d_in[9];
    const float* Ws1  = (const float*)d_in[10];
    const float* Wn1  = (const float*)d_in[11];
    const float* b1   = (const float*)d_in[12];
    const float* Ws2  = (const float*)d_in[13];
    const float* Wn2  = (const float*)d_in[14];
    const float* b2   = (const float*)d_in[15];
    const float* W_fc = (const float*)d_in[16];
    const float* b_fc = (const float*)d_in[17];
    float* out = (float*)d_out;

    // ---- workspace layout ----
    char* ws = (char*)d_ws;
    size_t off = 0;
    const size_t cntA_off = off; off = align256(off + (size_t)(N1 + N2 + N3) * 4); // zeroed region
    const size_t ptr0_off = off; off = align256(off + (size_t)(N1 + 1) * 4);
    const size_t ptr1_off = off; off = align256(off + (size_t)(N2 + 1) * 4);
    const size_t ptr2_off = off; off = align256(off + (size_t)(N3 + 1) * 4);
    const size_t cur0_off = off; off = align256(off + (size_t)N1 * 4);
    const size_t cur1_off = off; off = align256(off + (size_t)N2 * 4);
    const size_t cur2_off = off; off = align256(off + (size_t)N3 * 4);
    const size_t es0_off  = off; off = align256(off + (size_t)E0 * 4);
    const size_t es1_off  = off; off = align256(off + (size_t)E1 * 4);
    const size_t es2_off  = off; off = align256(off + (size_t)E2 * 4);
    const size_t xh_off   = off; off = align256(off + (size_t)N0 * D_IN * 2);   // full x fp16
    const size_t mean_off = off; off = align256(off + (size_t)N1 * D_IN * 2);
    const size_t h0_off   = off; off = align256(off + (size_t)N1 * D_H * 2);
    const size_t h1_off   = off; off = align256(off + (size_t)N2 * D_H * 2);
    const size_t h2_off   = off; off = align256(off + (size_t)N3 * D_H * 2);
    const size_t wt0_off  = off; off = align256(off + (size_t)D_IN * D_H * 2);  // WsT0
    const size_t wt1_off  = off; off = align256(off + (size_t)D_IN * D_H * 2);  // WnT0
    const size_t wt2_off  = off; off = align256(off + (size_t)D_H * D_H * 2);   // WsT1
    const size_t wt3_off  = off; off = align256(off + (size_t)D_H * D_H * 2);   // WnT1
    const size_t wt4_off  = off; off = align256(off + (size_t)D_H * D_H * 2);   // WsT2
    const size_t wt5_off  = off; off = align256(off + (size_t)D_H * D_H * 2);   // WnT2
    const size_t wt6_off  = off; off = align256(off + (size_t)D_H * D_H * 2);   // WfcT

    int* cnt0 = (int*)(ws + cntA_off);
    int* cnt1 = cnt0 + N1;
    int* cnt2 = cnt1 + N2;
    int* ptr0 = (int*)(ws + ptr0_off);
    int* ptr1 = (int*)(ws + ptr1_off);
    int* ptr2 = (int*)(ws + ptr2_off);
    int* cur0 = (int*)(ws + cur0_off);
    int* cur1 = (int*)(ws + cur1_off);
    int* cur2 = (int*)(ws + cur2_off);
    int* es0  = (int*)(ws + es0_off);
    int* es1  = (int*)(ws + es1_off);
    int* es2  = (int*)(ws + es2_off);
    half_t* xh   = (half_t*)(ws + xh_off);
    half_t* mean = (half_t*)(ws + mean_off);
    half_t* h0   = (half_t*)(ws + h0_off);
    half_t* h1   = (half_t*)(ws + h1_off);
    half_t* h2   = (half_t*)(ws + h2_off);
    half_t* WsT0 = (half_t*)(ws + wt0_off);
    half_t* WnT0 = (half_t*)(ws + wt1_off);
    half_t* WsT1 = (half_t*)(ws + wt2_off);
    half_t* WnT1 = (half_t*)(ws + wt3_off);
    half_t* WsT2 = (half_t*)(ws + wt4_off);
    half_t* WnT2 = (half_t*)(ws + wt5_off);
    half_t* WfcT = (half_t*)(ws + wt6_off);

    // ---- zero histograms, then fused conv+hist, scan, fill ----
    hipMemsetAsync(cnt0, 0, (size_t)(N1 + N2 + N3) * 4, stream);
    mega_conv_kernel<<<XB + WB + HB, 256, 0, stream>>>(
        x, xh,
        Ws0, Wn0, Ws1, Wn1, Ws2, Wn2, W_fc,
        WsT0, WnT0, WsT1, WnT1, WsT2, WnT2, WfcT,
        dst0, dst1, dst2, cnt0, cnt1, cnt2);
    scan3_kernel<<<3, 1024, 0, stream>>>(cnt0, ptr0, cur0, cnt1, ptr1, cur1, cnt2, ptr2, cur2);
    {
        const int tot = E0 + E1 + E2;
        fill3_kernel<<<(tot + 255) / 256, 256, 0, stream>>>(
            src0, dst0, src1, dst1, src2, dst2, cur0, cur1, cur2, es0, es1, es2);
    }

    // ---- layer 0 ----
    {
        constexpr int NPB = 256 / (D_IN / 8);   // 4 nodes / block
        csr_mean_f16<D_IN><<<(N1 + NPB - 1) / NPB, 256, 0, stream>>>(xh, es0, ptr0, mean, N1);
        mfma_gemm<true, true, true><<<(N1 + GBM - 1) / GBM, 512, 0, stream>>>(
            xh, mean, WsT0, WnT0, b0, h0, N1, D_IN);
    }
    // ---- layer 1 ----
    {
        constexpr int NPB = 256 / (D_H / 8);    // 8
        csr_mean_f16<D_H><<<(N2 + NPB - 1) / NPB, 256, 0, stream>>>(h0, es1, ptr1, mean, N2);
        mfma_gemm<true, true, true><<<(N2 + GBM - 1) / GBM, 512, 0, stream>>>(
            h0, mean, WsT1, WnT1, b1, h1, N2, D_H);
    }
    // ---- layer 2 (no relu) ----
    {
        constexpr int NPB = 256 / (D_H / 8);
        csr_mean_f16<D_H><<<(N3 + NPB - 1) / NPB, 256, 0, stream>>>(h1, es2, ptr2, mean, N3);
        mfma_gemm<true, false, true><<<(N3 + GBM - 1) / GBM, 512, 0, stream>>>(
            h1, mean, WsT2, WnT2, b2, h2, N3, D_H);
    }
    // ---- final FC (fp32 out) ----
    mfma_gemm<false, false, false><<<(N3 + GBM - 1) / GBM, 512, 0, stream>>>(
        h2, nullptr, WfcT, nullptr, b_fc, out, N3, D_H);
}